// Round 8
// baseline (566.974 us; speedup 1.0000x reference)
//
#include <hip/hip_runtime.h>

#define BB 32
#define DD 400
#define KK 200
#define NN (BB*KK)
#define NBINS 512

typedef float f2 __attribute__((ext_vector_type(2)));
typedef _Float16 half_t;
typedef _Float16 f16x2 __attribute__((ext_vector_type(2)));

#if defined(__has_builtin)
#if __has_builtin(__builtin_amdgcn_fdot2)
#define HAVE_FDOT2 1
#endif
#endif

__device__ __forceinline__ float dot2(f16x2 w, f16x2 v, float acc) {
#ifdef HAVE_FDOT2
  return __builtin_amdgcn_fdot2(w, v, acc, false);
#else
  return fmaf((float)w.x, (float)v.x, fmaf((float)w.y, (float)v.y, acc));
#endif
}

__device__ __forceinline__ float fast_sigmoid(float x) {
  float e = __builtin_amdgcn_exp2f(-1.4426950408889634f * x);
  return __builtin_amdgcn_rcpf(1.0f + e);
}
__device__ __forceinline__ float fast_tanh(float x) {
  float e = __builtin_amdgcn_exp2f(-2.8853900817779268f * x);
  return 2.0f * __builtin_amdgcn_rcpf(1.0f + e) - 1.0f;
}

// quad_perm broadcast P within each aligned 4-lane quad (VALU pipe, no LDS)
#define QPERM(v, P) __int_as_float(__builtin_amdgcn_mov_dpp(__float_as_int(v), (P)*0x55, 0xF, 0xF, true))
// lane ^ 4 exchange (BitMode swizzle: xor=4, and=0x1F)
#define SWZ_XOR4(v) __int_as_float(__builtin_amdgcn_ds_swizzle(__float_as_int(v), 0x101F))

// x (B, D, K) -> xt[(b*K+k)*D + t] = x[b][t][k]
__global__ __launch_bounds__(256) void transpose_x(const float* __restrict__ x,
                                                   float* __restrict__ xt) {
  __shared__ float tile[32][33];
  int b = blockIdx.x, t0 = blockIdx.y * 32, k0 = blockIdx.z * 32;
  int tx = threadIdx.x, ty = threadIdx.y;
#pragma unroll
  for (int i = 0; i < 32; i += 8) {
    int t = t0 + ty + i, k = k0 + tx;
    tile[ty + i][tx] = (t < DD && k < KK) ? x[((size_t)b * DD + t) * KK + k] : 0.0f;
  }
  __syncthreads();
#pragma unroll
  for (int i = 0; i < 32; i += 8) {
    int k = k0 + ty + i, t = t0 + tx;
    if (k < KK && t < DD) xt[((size_t)b * KK + k) * DD + t] = tile[tx][ty + i];
  }
}

// first zero index (else D) per sequence + length histogram
__global__ __launch_bounds__(64) void compute_lengths(const float* __restrict__ xt,
                                                      int* __restrict__ lengths,
                                                      int* __restrict__ hist) {
  int n = blockIdx.x, lane = threadIdx.x;
  int m = DD;
  for (int t = lane; t < DD; t += 64) {
    if (xt[(size_t)n * DD + t] == 0.0f) { m = t; break; }
  }
#pragma unroll
  for (int off = 1; off < 64; off <<= 1) {
    int o = __shfl_xor(m, off, 64);
    m = (o < m) ? o : m;
  }
  if (lane == 0) {
    lengths[n] = m;
    atomicAdd(&hist[m], 1);
  }
}

// wave-parallel exclusive prefix scan over 512 bins (8 bins/lane + shfl scan)
__global__ __launch_bounds__(64) void scan_offsets(const int* __restrict__ hist,
                                                   int* __restrict__ offs) {
  int lane = threadIdx.x;
  int v[8], tot = 0;
#pragma unroll
  for (int i = 0; i < 8; ++i) { v[i] = tot; tot += hist[lane * 8 + i]; }
  int incl = tot;
#pragma unroll
  for (int off = 1; off < 64; off <<= 1) {
    int oth = __shfl_up(incl, off, 64);
    if (lane >= off) incl += oth;
  }
  int excl = incl - tot;
#pragma unroll
  for (int i = 0; i < 8; ++i) offs[lane * 8 + i] = excl + v[i];
}

__global__ __launch_bounds__(256) void scatter_sort(const int* __restrict__ lengths,
                                                    int* __restrict__ offs,
                                                    int* __restrict__ order,
                                                    int* __restrict__ len_sorted) {
  int n = blockIdx.x * 256 + threadIdx.x;
  if (n >= NN) return;
  int len = lengths[n];
  int pos = atomicAdd(&offs[len], 1);
  order[pos] = n;
  len_sorted[pos] = len;
}

// ILP-2 GRU scan: each 8-lane group advances TWO sequences (adjacent sorted octets
// 2q and 2q+1) through one direction. Waves [0,Wp) = fwd, [Wp,2Wp) = bwd -> weights
// shared between both recurrences. Balance: wave pl takes pair q = pl&1 ? Wp-1-pl/2 : pl/2.
// gh math packed across recurrences: u = {hqA, hqB}, weights duplicated {w,w}.
// h-exchange: 1 ds_swizzle per rec (issued end of step) + 8 quad_perm DPP per rec.
template <int IN_DIM, bool IND_IN, bool WRITE_SEQ, bool FWD_ONLY>
__global__ __launch_bounds__(256, 1) void gru_scan(
    const void* __restrict__ in, half_t* __restrict__ out, float* __restrict__ feat,
    const int* __restrict__ len_sorted, const int* __restrict__ order,
    const float* __restrict__ Wih, const float* __restrict__ Whh,
    const float* __restrict__ bih, const float* __restrict__ bhh, int nseq) {
  int p = (blockIdx.x * 256 + threadIdx.x) >> 6;  // physical wave
  int lane = threadIdx.x & 63;
  int Wo = (nseq + 7) >> 3;       // octets per dir
  int Wp = (Wo + 1) >> 1;         // wave-slots per dir (2 octets each)
  int NW = FWD_ONLY ? Wp : 2 * Wp;
  if (p >= NW) return;
  int dirw = FWD_ONLY ? 0 : (p >= Wp ? 1 : 0);
  int pl = p - dirw * Wp;
  int q = (pl & 1) ? (Wp - 1 - (pl >> 1)) : (pl >> 1);
  int gi8 = lane >> 3, li = lane & 7;
  int sgA = (2 * q) * 8 + gi8;
  int sgB = (2 * q + 1) * 8 + gi8;
  bool vA = sgA < nseq, vB = sgB < nseq;
  int lenA = vA ? len_sorted[sgA] : 0;
  int lenB = vB ? len_sorted[sgB] : 0;
  int sgAc = vA ? sgA : 0, sgBc = vB ? sgB : 0;

  int qb = li & 4, qbx = qb ^ 4;
  f2 wAd[3][4], wBd[3][4];   // duplicated {w,w} for cross-recurrence packing
  f16x2 wi2[3][8];
  float wi1[3];
  float bs[3], bh2;          // bs[0..1] = bih+bhh, bs[2] = bih; bh2 = bhh n-gate
#pragma unroll
  for (int gt = 0; gt < 3; ++gt) {
    int row = dirw * 24 + gt * 8 + li;
    if constexpr (IN_DIM == 16) {
#pragma unroll
      for (int qq = 0; qq < 8; ++qq) {
        f16x2 w;
        w.x = (half_t)Wih[row * 16 + 2 * qq];
        w.y = (half_t)Wih[row * 16 + 2 * qq + 1];
        wi2[gt][qq] = w;
      }
    } else {
      wi1[gt] = Wih[row];
    }
#pragma unroll
    for (int P = 0; P < 4; ++P) {
      float wa = Whh[row * 8 + qb + P], wb = Whh[row * 8 + qbx + P];
      f2 da; da.x = wa; da.y = wa; wAd[gt][P] = da;
      f2 db; db.x = wb; db.y = wb; wBd[gt][P] = db;
    }
    bs[gt] = bih[row] + ((gt < 2) ? bhh[row] : 0.0f);
    if (gt == 2) bh2 = bhh[row];
  }

  int mx = (lenA > lenB) ? lenA : lenB;
  float hA = 0.0f, hxA = 0.0f, hB = 0.0f, hxB = 0.0f;

  ptrdiff_t xstep;
  const float *pxA = nullptr, *pxB = nullptr;
  const half_t *pxhA = nullptr, *pxhB = nullptr;
  if constexpr (IN_DIM == 1) {
    const float* basein = (const float*)in;
    const float* baseA = basein + (size_t)(IND_IN ? order[sgAc] : sgAc) * DD;
    const float* baseB = basein + (size_t)(IND_IN ? order[sgBc] : sgBc) * DD;
    pxA = baseA + ((dirw == 0) ? 0 : (lenA - 1));
    pxB = baseB + ((dirw == 0) ? 0 : (lenB - 1));
    xstep = (dirw == 0) ? 1 : -1;
  } else {
    const half_t* basein = (const half_t*)in;
    pxhA = basein + (size_t)sgAc * DD * 16 + (ptrdiff_t)((dirw == 0) ? 0 : (lenA - 1)) * 16;
    pxhB = basein + (size_t)sgBc * DD * 16 + (ptrdiff_t)((dirw == 0) ? 0 : (lenB - 1)) * 16;
    xstep = (dirw == 0) ? 16 : -16;
  }

  half_t *pwA = nullptr, *pwB = nullptr;
  ptrdiff_t wstep = 0;
  if constexpr (WRITE_SEQ) {
    pwA = out + ((size_t)sgAc * DD + ((dirw == 0) ? 0 : (lenA - 1))) * 16 + dirw * 8 + li;
    pwB = out + ((size_t)sgBc * DD + ((dirw == 0) ? 0 : (lenB - 1))) * 16 + dirw * 8 + li;
    wstep = (dirw == 0) ? 16 : -16;
  }

  // epilogue of one step-pair: packed gh, activations, predicated h update + store
  auto core2 = [&](float a0A, float a1A, float a2A,
                   float a0B, float a1B, float a2B, bool actA, bool actB) {
    float hqA0 = QPERM(hA, 0), hqA1 = QPERM(hA, 1), hqA2 = QPERM(hA, 2), hqA3 = QPERM(hA, 3);
    float hxA0 = QPERM(hxA, 0), hxA1 = QPERM(hxA, 1), hxA2 = QPERM(hxA, 2), hxA3 = QPERM(hxA, 3);
    float hqB0 = QPERM(hB, 0), hqB1 = QPERM(hB, 1), hqB2 = QPERM(hB, 2), hqB3 = QPERM(hB, 3);
    float hxB0 = QPERM(hxB, 0), hxB1 = QPERM(hxB, 1), hxB2 = QPERM(hxB, 2), hxB3 = QPERM(hxB, 3);
    f2 U0; U0.x = hqA0; U0.y = hqB0;
    f2 U1; U1.x = hqA1; U1.y = hqB1;
    f2 U2; U2.x = hqA2; U2.y = hqB2;
    f2 U3; U3.x = hqA3; U3.y = hqB3;
    f2 X0; X0.x = hxA0; X0.y = hxB0;
    f2 X1; X1.x = hxA1; X1.y = hxB1;
    f2 X2; X2.x = hxA2; X2.y = hxB2;
    f2 X3; X3.x = hxA3; X3.y = hxB3;

    f2 c0 = wAd[0][0] * U0; c0 += wAd[0][1] * U1; c0 += wAd[0][2] * U2; c0 += wAd[0][3] * U3;
    c0 += wBd[0][0] * X0; c0 += wBd[0][1] * X1; c0 += wBd[0][2] * X2; c0 += wBd[0][3] * X3;
    f2 c1 = wAd[1][0] * U0; c1 += wAd[1][1] * U1; c1 += wAd[1][2] * U2; c1 += wAd[1][3] * U3;
    c1 += wBd[1][0] * X0; c1 += wBd[1][1] * X1; c1 += wBd[1][2] * X2; c1 += wBd[1][3] * X3;
    f2 c2; c2.x = bh2; c2.y = bh2;
    c2 += wAd[2][0] * U0; c2 += wAd[2][1] * U1; c2 += wAd[2][2] * U2; c2 += wAd[2][3] * U3;
    c2 += wBd[2][0] * X0; c2 += wBd[2][1] * X1; c2 += wBd[2][2] * X2; c2 += wBd[2][3] * X3;

    float rA = fast_sigmoid(a0A + c0.x), rB = fast_sigmoid(a0B + c0.y);
    float zA = fast_sigmoid(a1A + c1.x), zB = fast_sigmoid(a1B + c1.y);
    float nA = fast_tanh(a2A + rA * c2.x), nB = fast_tanh(a2B + rB * c2.y);
    float hAn = zA * (hA - nA) + nA;
    float hBn = zB * (hB - nB) + nB;
    hA = actA ? hAn : hA;
    hB = actB ? hBn : hB;
    hxA = SWZ_XOR4(hA);
    hxB = SWZ_XOR4(hB);
    if constexpr (WRITE_SEQ) {
      if (actA) *pwA = (half_t)hA;
      if (actB) *pwB = (half_t)hB;
      pwA += wstep; pwB += wstep;
    }
  };

  if constexpr (IN_DIM == 1) {
    float sA0_, sA1_, sA2_, sA3_, sB0_, sB1_, sB2_, sB3_;
    auto ldA = [&](float& S_) { S_ = *pxA; pxA += xstep; };
    auto ldB = [&](float& S_) { S_ = *pxB; pxB += xstep; };
    auto st = [&](float& SA_, float& SB_, int t, bool pf) {
      float a0A = fmaf(wi1[0], SA_, bs[0]);
      float a1A = fmaf(wi1[1], SA_, bs[1]);
      float a2A = fmaf(wi1[2], SA_, bs[2]);
      float a0B = fmaf(wi1[0], SB_, bs[0]);
      float a1B = fmaf(wi1[1], SB_, bs[1]);
      float a2B = fmaf(wi1[2], SB_, bs[2]);
      if (pf) { ldA(SA_); ldB(SB_); }
      core2(a0A, a1A, a2A, a0B, a1B, a2B, t < lenA, t < lenB);
    };
    ldA(sA0_); ldB(sB0_); ldA(sA1_); ldB(sB1_);
    ldA(sA2_); ldB(sB2_); ldA(sA3_); ldB(sB3_);
    int t = 0;
    for (; t + 4 <= mx; t += 4) {
      st(sA0_, sB0_, t, true); st(sA1_, sB1_, t + 1, true);
      st(sA2_, sB2_, t + 2, true); st(sA3_, sB3_, t + 3, true);
    }
    int rem = mx - t;
    if (rem > 0) st(sA0_, sB0_, t, false);
    if (rem > 1) st(sA1_, sB1_, t + 1, false);
    if (rem > 2) st(sA2_, sB2_, t + 2, false);
  } else {
    uint4 bA0_[2], bA1_[2], bA2_[2], bA3_[2];
    uint4 bB0_[2], bB1_[2], bB2_[2], bB3_[2];
    auto ldA = [&](uint4 (&B_)[2]) {
      const uint4* q4 = reinterpret_cast<const uint4*>(pxhA);
      B_[0] = q4[0]; B_[1] = q4[1];
      pxhA += xstep;
    };
    auto ldB = [&](uint4 (&B_)[2]) {
      const uint4* q4 = reinterpret_cast<const uint4*>(pxhB);
      B_[0] = q4[0]; B_[1] = q4[1];
      pxhB += xstep;
    };
    auto gi3 = [&](uint4 (&B_)[2], float& a0, float& a1, float& a2) {
      a0 = bs[0]; a1 = bs[1]; a2 = bs[2];
#pragma unroll
      for (int qq = 0; qq < 2; ++qq) {
        f16x2 p0 = __builtin_bit_cast(f16x2, B_[qq].x);
        f16x2 p1 = __builtin_bit_cast(f16x2, B_[qq].y);
        f16x2 p2 = __builtin_bit_cast(f16x2, B_[qq].z);
        f16x2 p3 = __builtin_bit_cast(f16x2, B_[qq].w);
        a0 = dot2(wi2[0][4*qq], p0, a0); a0 = dot2(wi2[0][4*qq+1], p1, a0);
        a0 = dot2(wi2[0][4*qq+2], p2, a0); a0 = dot2(wi2[0][4*qq+3], p3, a0);
        a1 = dot2(wi2[1][4*qq], p0, a1); a1 = dot2(wi2[1][4*qq+1], p1, a1);
        a1 = dot2(wi2[1][4*qq+2], p2, a1); a1 = dot2(wi2[1][4*qq+3], p3, a1);
        a2 = dot2(wi2[2][4*qq], p0, a2); a2 = dot2(wi2[2][4*qq+1], p1, a2);
        a2 = dot2(wi2[2][4*qq+2], p2, a2); a2 = dot2(wi2[2][4*qq+3], p3, a2);
      }
    };
    auto st = [&](uint4 (&A_)[2], uint4 (&B_)[2], int t, bool pf) {
      float a0A, a1A, a2A, a0B, a1B, a2B;
      gi3(A_, a0A, a1A, a2A);
      gi3(B_, a0B, a1B, a2B);
      if (pf) { ldA(A_); ldB(B_); }
      core2(a0A, a1A, a2A, a0B, a1B, a2B, t < lenA, t < lenB);
    };
    ldA(bA0_); ldB(bB0_); ldA(bA1_); ldB(bB1_);
    ldA(bA2_); ldB(bB2_); ldA(bA3_); ldB(bB3_);
    int t = 0;
    for (; t + 4 <= mx; t += 4) {
      st(bA0_, bB0_, t, true); st(bA1_, bB1_, t + 1, true);
      st(bA2_, bB2_, t + 2, true); st(bA3_, bB3_, t + 3, true);
    }
    int rem = mx - t;
    if (rem > 0) st(bA0_, bB0_, t, false);
    if (rem > 1) st(bA1_, bB1_, t + 1, false);
    if (rem > 2) st(bA2_, bB2_, t + 2, false);
  }

  if constexpr (!WRITE_SEQ) {
    if (vA) feat[(size_t)order[sgA] * 16 + dirw * 8 + li] = hA;
    if (vB) feat[(size_t)order[sgB] * 16 + dirw * 8 + li] = hB;
  }
}

// last layer, bwd direction: only t = len-1 matters and h0 = 0 => gh = bhh (closed form)
__global__ __launch_bounds__(256) void bwd_last(
    const half_t* __restrict__ in, float* __restrict__ feat,
    const int* __restrict__ len_sorted, const int* __restrict__ order,
    const float* __restrict__ Wih, const float* __restrict__ bih,
    const float* __restrict__ bhh, int nseq) {
  int tid = blockIdx.x * blockDim.x + threadIdx.x;
  int sg = tid >> 3, li = tid & 7;
  if (sg >= nseq) return;
  int len = len_sorted[sg];
  const half_t* xp = in + ((size_t)sg * DD + (len - 1)) * 16;
  float xv[16];
#pragma unroll
  for (int j = 0; j < 16; ++j) xv[j] = (float)xp[j];
  float a[3], bh[3];
#pragma unroll
  for (int gt = 0; gt < 3; ++gt) {
    int row = 24 + gt * 8 + li;  // dir=1 rows
    const float* wp = Wih + row * 16;
    float acc = bih[row];
#pragma unroll
    for (int j = 0; j < 16; ++j) acc = fmaf(wp[j], xv[j], acc);
    a[gt] = acc;
    bh[gt] = bhh[row];
  }
  float r = fast_sigmoid(a[0] + bh[0]);
  float z = fast_sigmoid(a[1] + bh[1]);
  float n = fast_tanh(a[2] + r * bh[2]);
  float h = (1.0f - z) * n;
  feat[(size_t)order[sg] * 16 + 8 + li] = h;
}

__global__ __launch_bounds__(256) void head_kernel(
    const float* __restrict__ feat, const float* __restrict__ w1,
    const float* __restrict__ b1, const float* __restrict__ w2,
    const float* __restrict__ b2, float* __restrict__ out) {
  int n = blockIdx.x * blockDim.x + threadIdx.x;
  if (n >= NN) return;
  float f[16];
  const float4* p = reinterpret_cast<const float4*>(feat + (size_t)n * 16);
#pragma unroll
  for (int q = 0; q < 4; ++q) {
    float4 v = p[q];
    f[4*q] = v.x; f[4*q+1] = v.y; f[4*q+2] = v.z; f[4*q+3] = v.w;
  }
  float y[8];
#pragma unroll
  for (int o = 0; o < 8; ++o) {
    float s = b1[o];
#pragma unroll
    for (int j = 0; j < 16; ++j) s += f[j] * w1[o * 16 + j];
    y[o] = (s > 0.0f) ? s : 0.2f * s;
  }
#pragma unroll
  for (int o2 = 0; o2 < 8; ++o2) {
    float s = b2[o2];
#pragma unroll
    for (int o = 0; o < 8; ++o) s += y[o] * w2[o2 * 8 + o];
    out[(size_t)n * 8 + o2] = s;
  }
}

extern "C" void kernel_launch(void* const* d_in, const int* in_sizes, int n_in,
                              void* d_out, int out_size, void* d_ws, size_t ws_size,
                              hipStream_t stream) {
  const float* x      = (const float*)d_in[0];
  const float* w_ih0  = (const float*)d_in[1];
  const float* w_hh0  = (const float*)d_in[2];
  const float* b_ih0  = (const float*)d_in[3];
  const float* b_hh0  = (const float*)d_in[4];
  const float* w_ih   = (const float*)d_in[5];
  const float* w_hh   = (const float*)d_in[6];
  const float* b_ih   = (const float*)d_in[7];
  const float* b_hh   = (const float*)d_in[8];
  const float* lin1_w = (const float*)d_in[9];
  const float* lin1_b = (const float*)d_in[10];
  const float* lin2_w = (const float*)d_in[11];
  const float* lin2_b = (const float*)d_in[12];
  float* out = (float*)d_out;

  char* ws = (char*)d_ws;
  size_t off = 0;
  auto alloc = [&](size_t bytes) -> void* {
    void* p = ws + off;
    off += (bytes + 255) & ~(size_t)255;
    return p;
  };
  alloc(1024);  // front guard (backward prefetch overrun)
  float* xt         = (float*)alloc((size_t)NN * DD * sizeof(float) + 1024);
  int*   lengths    = (int*)  alloc((size_t)NN * sizeof(int));
  int*   hist       = (int*)  alloc(NBINS * sizeof(int));
  int*   offs       = (int*)  alloc(NBINS * sizeof(int));
  int*   order      = (int*)  alloc((size_t)NN * sizeof(int));
  int*   len_sorted = (int*)  alloc((size_t)NN * sizeof(int));
  float* feat       = (float*)alloc((size_t)NN * 16 * sizeof(float));
  size_t base = off;
  size_t per_seq = (size_t)DD * 16 * sizeof(half_t) * 2 + 1024;  // two f16 ping-pong buffers
  int Nc = NN;
  if (base + (size_t)NN * per_seq + 8192 > ws_size) {
    size_t avail = (ws_size > base + 8192) ? (ws_size - base - 8192) : 0;
    size_t nc = avail / per_seq;
    if (nc < 1) nc = 1;
    if (nc > (size_t)NN) nc = NN;
    Nc = (int)nc;
  }
  alloc(1024);  // guard before bufA
  half_t* bufA = (half_t*)alloc((size_t)Nc * DD * 16 * sizeof(half_t) + 1024);
  half_t* bufB = (half_t*)alloc((size_t)Nc * DD * 16 * sizeof(half_t) + 1024);

  hipMemsetAsync(hist, 0, NBINS * sizeof(int), stream);
  dim3 gT(BB, (DD + 31) / 32, (KK + 31) / 32), bT(32, 8, 1);
  hipLaunchKernelGGL(transpose_x, gT, bT, 0, stream, x, xt);
  hipLaunchKernelGGL(compute_lengths, dim3(NN), dim3(64), 0, stream, xt, lengths, hist);
  hipLaunchKernelGGL(scan_offsets, dim3(1), dim3(64), 0, stream, hist, offs);
  hipLaunchKernelGGL(scatter_sort, dim3((NN + 255) / 256), dim3(256), 0, stream,
                     lengths, offs, order, len_sorted);

  for (int s0 = 0; s0 < NN; s0 += Nc) {
    int ns = (NN - s0 < Nc) ? (NN - s0) : Nc;
    int Wo = (ns + 7) / 8;
    int Wp = (Wo + 1) / 2;
    int blk2 = (2 * Wp + 3) / 4;       // bidir: 2*Wp waves, 4 waves/block
    int blk1f = (Wp + 3) / 4;          // fwd-only
    int blk1 = (ns * 8 + 255) / 256;   // bwd_last
    gru_scan<1, true, true, false><<<blk2, 256, 0, stream>>>(
        (const void*)xt, bufA, nullptr, len_sorted + s0, order + s0,
        w_ih0, w_hh0, b_ih0, b_hh0, ns);
    gru_scan<16, false, true, false><<<blk2, 256, 0, stream>>>(
        (const void*)bufA, bufB, nullptr, len_sorted + s0, order + s0,
        w_ih + 0 * 2 * 24 * 16, w_hh + 0 * 2 * 24 * 8,
        b_ih + 0 * 2 * 24, b_hh + 0 * 2 * 24, ns);
    gru_scan<16, false, true, false><<<blk2, 256, 0, stream>>>(
        (const void*)bufB, bufA, nullptr, len_sorted + s0, order + s0,
        w_ih + 1 * 2 * 24 * 16, w_hh + 1 * 2 * 24 * 8,
        b_ih + 1 * 2 * 24, b_hh + 1 * 2 * 24, ns);
    gru_scan<16, false, false, true><<<blk1f, 256, 0, stream>>>(
        (const void*)bufA, nullptr, feat, len_sorted + s0, order + s0,
        w_ih + 2 * 2 * 24 * 16, w_hh + 2 * 2 * 24 * 8,
        b_ih + 2 * 2 * 24, b_hh + 2 * 2 * 24, ns);
    hipLaunchKernelGGL(bwd_last, dim3(blk1), dim3(256), 0, stream,
                       bufA, feat, len_sorted + s0, order + s0,
                       w_ih + 2 * 2 * 24 * 16, b_ih + 2 * 2 * 24, b_hh + 2 * 2 * 24, ns);
  }
  hipLaunchKernelGGL(head_kernel, dim3((NN + 255) / 256), dim3(256), 0, stream,
                     feat, lin1_w, lin1_b, lin2_w, lin2_b, out);
}

// Round 9
// 462.160 us; speedup vs baseline: 1.2268x; 1.2268x over previous
//
#include <hip/hip_runtime.h>

#define BB 32
#define DD 400
#define KK 200
#define NN (BB*KK)
#define NBINS 512

typedef float f2 __attribute__((ext_vector_type(2)));
typedef _Float16 half_t;
typedef _Float16 f16x2 __attribute__((ext_vector_type(2)));

#if defined(__has_builtin)
#if __has_builtin(__builtin_amdgcn_fdot2)
#define HAVE_FDOT2 1
#endif
#endif

__device__ __forceinline__ float dot2(f16x2 w, f16x2 v, float acc) {
#ifdef HAVE_FDOT2
  return __builtin_amdgcn_fdot2(w, v, acc, false);
#else
  return fmaf((float)w.x, (float)v.x, fmaf((float)w.y, (float)v.y, acc));
#endif
}

__device__ __forceinline__ float fast_sigmoid(float x) {
  float e = __builtin_amdgcn_exp2f(-1.4426950408889634f * x);
  return __builtin_amdgcn_rcpf(1.0f + e);
}
__device__ __forceinline__ float fast_tanh(float x) {
  float e = __builtin_amdgcn_exp2f(-2.8853900817779268f * x);
  return 2.0f * __builtin_amdgcn_rcpf(1.0f + e) - 1.0f;
}

// quad_perm broadcast P within each aligned 4-lane quad (VALU pipe)
#define QPERM(v, P) __int_as_float(__builtin_amdgcn_mov_dpp(__float_as_int(v), (P)*0x55, 0xF, 0xF, true))
// ROW_HALF_MIRROR: lane i reads lane i^7 within each 8-lane half-row (VALU pipe, no LDS!)
#define HMIRROR(v) __int_as_float(__builtin_amdgcn_mov_dpp(__float_as_int(v), 0x141, 0xF, 0xF, true))

// x (B, D, K) -> xt[(b*K+k)*D + t] = x[b][t][k]
__global__ __launch_bounds__(256) void transpose_x(const float* __restrict__ x,
                                                   float* __restrict__ xt) {
  __shared__ float tile[32][33];
  int b = blockIdx.x, t0 = blockIdx.y * 32, k0 = blockIdx.z * 32;
  int tx = threadIdx.x, ty = threadIdx.y;
#pragma unroll
  for (int i = 0; i < 32; i += 8) {
    int t = t0 + ty + i, k = k0 + tx;
    tile[ty + i][tx] = (t < DD && k < KK) ? x[((size_t)b * DD + t) * KK + k] : 0.0f;
  }
  __syncthreads();
#pragma unroll
  for (int i = 0; i < 32; i += 8) {
    int k = k0 + ty + i, t = t0 + tx;
    if (k < KK && t < DD) xt[((size_t)b * KK + k) * DD + t] = tile[tx][ty + i];
  }
}

// first zero index (else D) per sequence + length histogram
__global__ __launch_bounds__(64) void compute_lengths(const float* __restrict__ xt,
                                                      int* __restrict__ lengths,
                                                      int* __restrict__ hist) {
  int n = blockIdx.x, lane = threadIdx.x;
  int m = DD;
  for (int t = lane; t < DD; t += 64) {
    if (xt[(size_t)n * DD + t] == 0.0f) { m = t; break; }
  }
#pragma unroll
  for (int off = 1; off < 64; off <<= 1) {
    int o = __shfl_xor(m, off, 64);
    m = (o < m) ? o : m;
  }
  if (lane == 0) {
    lengths[n] = m;
    atomicAdd(&hist[m], 1);
  }
}

// wave-parallel exclusive prefix scan over 512 bins (8 bins/lane + shfl scan)
__global__ __launch_bounds__(64) void scan_offsets(const int* __restrict__ hist,
                                                   int* __restrict__ offs) {
  int lane = threadIdx.x;
  int v[8], tot = 0;
#pragma unroll
  for (int i = 0; i < 8; ++i) { v[i] = tot; tot += hist[lane * 8 + i]; }
  int incl = tot;
#pragma unroll
  for (int off = 1; off < 64; off <<= 1) {
    int oth = __shfl_up(incl, off, 64);
    if (lane >= off) incl += oth;
  }
  int excl = incl - tot;
#pragma unroll
  for (int i = 0; i < 8; ++i) offs[lane * 8 + i] = excl + v[i];
}

__global__ __launch_bounds__(256) void scatter_sort(const int* __restrict__ lengths,
                                                    int* __restrict__ offs,
                                                    int* __restrict__ order,
                                                    int* __restrict__ len_sorted) {
  int n = blockIdx.x * 256 + threadIdx.x;
  if (n >= NN) return;
  int len = lengths[n];
  int pos = atomicAdd(&offs[len], 1);
  order[pos] = n;
  len_sorted[pos] = len;
}

// 8 lanes per (sorted-seq, dir); lane li owns hidden unit li.
// Work balance: physical wave p takes sorted wave-octet p/2 (even) or W-1-p/2 (odd).
// h-exchange: ALL-DPP (half_mirror + quad_perm) -> zero LDS ops in the scan loop.
// QPERM(HMIRROR(h), P) = h[(qb+P)^7], so wAB.y uses Whh column (qb+P)^7.
// Inter-layer streams f16; gi dots via v_dot2_f32_f16. 4-step register prefetch.
template <int IN_DIM, bool IND_IN, bool WRITE_SEQ, bool FWD_ONLY>
__global__ __launch_bounds__(256) void gru_scan(
    const void* __restrict__ in, half_t* __restrict__ out, float* __restrict__ feat,
    const int* __restrict__ len_sorted, const int* __restrict__ order,
    const float* __restrict__ Wih, const float* __restrict__ Whh,
    const float* __restrict__ bih, const float* __restrict__ bhh, int nseq) {
  int p = (blockIdx.x * 256 + threadIdx.x) >> 6;  // physical wave
  int lane = threadIdx.x & 63;
  int G = FWD_ONLY ? nseq : nseq * 2;
  int W = (G + 7) >> 3;
  if (p >= W) return;
  int o = (p & 1) ? (W - 1 - (p >> 1)) : (p >> 1);
  int gidx = o * 8 + (lane >> 3);
  int li = lane & 7;
  if (gidx >= G) return;
  int sg  = FWD_ONLY ? gidx : (gidx >> 1);
  int dir = FWD_ONLY ? 0 : (gidx & 1);
  int len = len_sorted[sg];

  int qb = li & 4;
  f2 wAB[3][4];       // {wA: col qb+P, wB: col (qb+P)^7} for packed gh
  f16x2 wi2[3][8];
  float wi1[3];
  float bs[3], bh2;   // bs[0..1] = bih+bhh, bs[2] = bih; bh2 = bhh n-gate
#pragma unroll
  for (int gt = 0; gt < 3; ++gt) {
    int row = dir * 24 + gt * 8 + li;
    if constexpr (IN_DIM == 16) {
#pragma unroll
      for (int q = 0; q < 8; ++q) {
        f16x2 w;
        w.x = (half_t)Wih[row * 16 + 2 * q];
        w.y = (half_t)Wih[row * 16 + 2 * q + 1];
        wi2[gt][q] = w;
      }
    } else {
      wi1[gt] = Wih[row];
    }
#pragma unroll
    for (int P = 0; P < 4; ++P) {
      f2 w;
      w.x = Whh[row * 8 + qb + P];
      w.y = Whh[row * 8 + ((qb + P) ^ 7)];
      wAB[gt][P] = w;
    }
    bs[gt] = bih[row] + ((gt < 2) ? bhh[row] : 0.0f);
    if (gt == 2) bh2 = bhh[row];
  }

  int steps = len;  // >= 200 always
  float h = 0.0f;

  const float* px = nullptr;
  const half_t* pxh = nullptr;
  ptrdiff_t xstep;
  if constexpr (IN_DIM == 1) {
    const float* basep = (const float*)in + (IND_IN ? (size_t)order[sg] * DD : (size_t)sg * DD);
    px = basep + ((dir == 0) ? 0 : (len - 1));
    xstep = (dir == 0) ? 1 : -1;
  } else {
    const half_t* basep = (const half_t*)in + (size_t)sg * DD * 16;
    pxh = basep + (size_t)((dir == 0) ? 0 : (len - 1)) * 16;
    xstep = (dir == 0) ? 16 : -16;
  }

  half_t* pw = nullptr; ptrdiff_t wstep = 0;
  if constexpr (WRITE_SEQ) {
    pw = out + ((size_t)sg * DD + ((dir == 0) ? 0 : (len - 1))) * 16 + dir * 8 + li;
    wstep = (dir == 0) ? 16 : -16;
  }

  // shared epilogue: all-DPP h-gather, packed gh, activations, h update, store
  auto core = [&](float a0, float a1, float a2) {
    float hm = HMIRROR(h);  // lane i^7's h (cross-quad), pure VALU
    float hq0 = QPERM(h, 0), hq1 = QPERM(h, 1), hq2 = QPERM(h, 2), hq3 = QPERM(h, 3);
    float hx0 = QPERM(hm, 0), hx1 = QPERM(hm, 1), hx2 = QPERM(hm, 2), hx3 = QPERM(hm, 3);
    f2 u0; u0.x = hq0; u0.y = hx0;
    f2 u1; u1.x = hq1; u1.y = hx1;
    f2 u2; u2.x = hq2; u2.y = hx2;
    f2 u3; u3.x = hq3; u3.y = hx3;

    f2 c0 = wAB[0][0] * u0; c0 += wAB[0][1] * u1; c0 += wAB[0][2] * u2; c0 += wAB[0][3] * u3;
    f2 c1 = wAB[1][0] * u0; c1 += wAB[1][1] * u1; c1 += wAB[1][2] * u2; c1 += wAB[1][3] * u3;
    f2 c2; c2.x = bh2; c2.y = 0.0f;
    c2 += wAB[2][0] * u0; c2 += wAB[2][1] * u1; c2 += wAB[2][2] * u2; c2 += wAB[2][3] * u3;

    float r = fast_sigmoid(a0 + c0.x + c0.y);
    float z = fast_sigmoid(a1 + c1.x + c1.y);
    float n = fast_tanh(a2 + r * (c2.x + c2.y));
    h = z * (h - n) + n;  // == (1-z)*n + z*h
    if constexpr (WRITE_SEQ) { *pw = (half_t)h; pw += wstep; }
  };

  if constexpr (IN_DIM == 1) {
    float s0_, s1_, s2_, s3_;
    auto ld = [&](float& S_) { S_ = *px; px += xstep; };
    auto st = [&](float& S_, bool pf) {
      float a0 = fmaf(wi1[0], S_, bs[0]);
      float a1 = fmaf(wi1[1], S_, bs[1]);
      float a2 = fmaf(wi1[2], S_, bs[2]);
      if (pf) ld(S_);
      core(a0, a1, a2);
    };
    ld(s0_); ld(s1_); ld(s2_); ld(s3_);
    int t = 0;
    for (; t + 4 <= steps; t += 4) {
      st(s0_, true); st(s1_, true); st(s2_, true); st(s3_, true);
    }
    int rem = steps - t;
    if (rem > 0) st(s0_, false);
    if (rem > 1) st(s1_, false);
    if (rem > 2) st(s2_, false);
  } else {
    uint4 b0_[2], b1_[2], b2_[2], b3_[2];
    auto ld = [&](uint4 (&B_)[2]) {
      const uint4* q4 = reinterpret_cast<const uint4*>(pxh);
      B_[0] = q4[0]; B_[1] = q4[1];
      pxh += xstep;
    };
    auto st = [&](uint4 (&B_)[2], bool pf) {
      float a0 = bs[0], a1 = bs[1], a2 = bs[2];
#pragma unroll
      for (int q = 0; q < 2; ++q) {
        f16x2 p0 = __builtin_bit_cast(f16x2, B_[q].x);
        f16x2 p1 = __builtin_bit_cast(f16x2, B_[q].y);
        f16x2 p2 = __builtin_bit_cast(f16x2, B_[q].z);
        f16x2 p3 = __builtin_bit_cast(f16x2, B_[q].w);
        a0 = dot2(wi2[0][4*q], p0, a0); a0 = dot2(wi2[0][4*q+1], p1, a0);
        a0 = dot2(wi2[0][4*q+2], p2, a0); a0 = dot2(wi2[0][4*q+3], p3, a0);
        a1 = dot2(wi2[1][4*q], p0, a1); a1 = dot2(wi2[1][4*q+1], p1, a1);
        a1 = dot2(wi2[1][4*q+2], p2, a1); a1 = dot2(wi2[1][4*q+3], p3, a1);
        a2 = dot2(wi2[2][4*q], p0, a2); a2 = dot2(wi2[2][4*q+1], p1, a2);
        a2 = dot2(wi2[2][4*q+2], p2, a2); a2 = dot2(wi2[2][4*q+3], p3, a2);
      }
      if (pf) ld(B_);
      core(a0, a1, a2);
    };
    ld(b0_); ld(b1_); ld(b2_); ld(b3_);
    int t = 0;
    for (; t + 4 <= steps; t += 4) {
      st(b0_, true); st(b1_, true); st(b2_, true); st(b3_, true);
    }
    int rem = steps - t;
    if (rem > 0) st(b0_, false);
    if (rem > 1) st(b1_, false);
    if (rem > 2) st(b2_, false);
  }

  if constexpr (!WRITE_SEQ) {
    feat[(size_t)order[sg] * 16 + dir * 8 + li] = h;
  }
}

// last layer, bwd direction: only t = len-1 matters and h0 = 0 => gh = bhh (closed form)
__global__ __launch_bounds__(256) void bwd_last(
    const half_t* __restrict__ in, float* __restrict__ feat,
    const int* __restrict__ len_sorted, const int* __restrict__ order,
    const float* __restrict__ Wih, const float* __restrict__ bih,
    const float* __restrict__ bhh, int nseq) {
  int tid = blockIdx.x * blockDim.x + threadIdx.x;
  int sg = tid >> 3, li = tid & 7;
  if (sg >= nseq) return;
  int len = len_sorted[sg];
  const half_t* xp = in + ((size_t)sg * DD + (len - 1)) * 16;
  float xv[16];
#pragma unroll
  for (int j = 0; j < 16; ++j) xv[j] = (float)xp[j];
  float a[3], bh[3];
#pragma unroll
  for (int gt = 0; gt < 3; ++gt) {
    int row = 24 + gt * 8 + li;  // dir=1 rows
    const float* wp = Wih + row * 16;
    float acc = bih[row];
#pragma unroll
    for (int j = 0; j < 16; ++j) acc = fmaf(wp[j], xv[j], acc);
    a[gt] = acc;
    bh[gt] = bhh[row];
  }
  float r = fast_sigmoid(a[0] + bh[0]);
  float z = fast_sigmoid(a[1] + bh[1]);
  float n = fast_tanh(a[2] + r * bh[2]);
  float h = (1.0f - z) * n;
  feat[(size_t)order[sg] * 16 + 8 + li] = h;
}

__global__ __launch_bounds__(256) void head_kernel(
    const float* __restrict__ feat, const float* __restrict__ w1,
    const float* __restrict__ b1, const float* __restrict__ w2,
    const float* __restrict__ b2, float* __restrict__ out) {
  int n = blockIdx.x * blockDim.x + threadIdx.x;
  if (n >= NN) return;
  float f[16];
  const float4* p = reinterpret_cast<const float4*>(feat + (size_t)n * 16);
#pragma unroll
  for (int q = 0; q < 4; ++q) {
    float4 v = p[q];
    f[4*q] = v.x; f[4*q+1] = v.y; f[4*q+2] = v.z; f[4*q+3] = v.w;
  }
  float y[8];
#pragma unroll
  for (int o = 0; o < 8; ++o) {
    float s = b1[o];
#pragma unroll
    for (int j = 0; j < 16; ++j) s += f[j] * w1[o * 16 + j];
    y[o] = (s > 0.0f) ? s : 0.2f * s;
  }
#pragma unroll
  for (int o2 = 0; o2 < 8; ++o2) {
    float s = b2[o2];
#pragma unroll
    for (int o = 0; o < 8; ++o) s += y[o] * w2[o2 * 8 + o];
    out[(size_t)n * 8 + o2] = s;
  }
}

extern "C" void kernel_launch(void* const* d_in, const int* in_sizes, int n_in,
                              void* d_out, int out_size, void* d_ws, size_t ws_size,
                              hipStream_t stream) {
  const float* x      = (const float*)d_in[0];
  const float* w_ih0  = (const float*)d_in[1];
  const float* w_hh0  = (const float*)d_in[2];
  const float* b_ih0  = (const float*)d_in[3];
  const float* b_hh0  = (const float*)d_in[4];
  const float* w_ih   = (const float*)d_in[5];
  const float* w_hh   = (const float*)d_in[6];
  const float* b_ih   = (const float*)d_in[7];
  const float* b_hh   = (const float*)d_in[8];
  const float* lin1_w = (const float*)d_in[9];
  const float* lin1_b = (const float*)d_in[10];
  const float* lin2_w = (const float*)d_in[11];
  const float* lin2_b = (const float*)d_in[12];
  float* out = (float*)d_out;

  char* ws = (char*)d_ws;
  size_t off = 0;
  auto alloc = [&](size_t bytes) -> void* {
    void* p = ws + off;
    off += (bytes + 255) & ~(size_t)255;
    return p;
  };
  alloc(1024);  // front guard (backward prefetch overrun)
  float* xt         = (float*)alloc((size_t)NN * DD * sizeof(float) + 1024);
  int*   lengths    = (int*)  alloc((size_t)NN * sizeof(int));
  int*   hist       = (int*)  alloc(NBINS * sizeof(int));
  int*   offs       = (int*)  alloc(NBINS * sizeof(int));
  int*   order      = (int*)  alloc((size_t)NN * sizeof(int));
  int*   len_sorted = (int*)  alloc((size_t)NN * sizeof(int));
  float* feat       = (float*)alloc((size_t)NN * 16 * sizeof(float));
  size_t base = off;
  size_t per_seq = (size_t)DD * 16 * sizeof(half_t) * 2 + 1024;  // two f16 ping-pong buffers
  int Nc = NN;
  if (base + (size_t)NN * per_seq + 8192 > ws_size) {
    size_t avail = (ws_size > base + 8192) ? (ws_size - base - 8192) : 0;
    size_t nc = avail / per_seq;
    if (nc < 1) nc = 1;
    if (nc > (size_t)NN) nc = NN;
    Nc = (int)nc;
  }
  alloc(1024);  // guard before bufA
  half_t* bufA = (half_t*)alloc((size_t)Nc * DD * 16 * sizeof(half_t) + 1024);
  half_t* bufB = (half_t*)alloc((size_t)Nc * DD * 16 * sizeof(half_t) + 1024);

  hipMemsetAsync(hist, 0, NBINS * sizeof(int), stream);
  dim3 gT(BB, (DD + 31) / 32, (KK + 31) / 32), bT(32, 8, 1);
  hipLaunchKernelGGL(transpose_x, gT, bT, 0, stream, x, xt);
  hipLaunchKernelGGL(compute_lengths, dim3(NN), dim3(64), 0, stream, xt, lengths, hist);
  hipLaunchKernelGGL(scan_offsets, dim3(1), dim3(64), 0, stream, hist, offs);
  hipLaunchKernelGGL(scatter_sort, dim3((NN + 255) / 256), dim3(256), 0, stream,
                     lengths, offs, order, len_sorted);

  for (int s0 = 0; s0 < NN; s0 += Nc) {
    int ns = (NN - s0 < Nc) ? (NN - s0) : Nc;
    int W2 = (ns * 2 + 7) / 8;           // bidir wave count
    int W1 = (ns + 7) / 8;               // fwd-only wave count
    int blk2 = (W2 + 3) / 4;
    int blk1f = (W1 + 3) / 4;
    int blk1 = (ns * 8 + 255) / 256;     // bwd_last
    gru_scan<1, true, true, false><<<blk2, 256, 0, stream>>>(
        (const void*)xt, bufA, nullptr, len_sorted + s0, order + s0,
        w_ih0, w_hh0, b_ih0, b_hh0, ns);
    gru_scan<16, false, true, false><<<blk2, 256, 0, stream>>>(
        (const void*)bufA, bufB, nullptr, len_sorted + s0, order + s0,
        w_ih + 0 * 2 * 24 * 16, w_hh + 0 * 2 * 24 * 8,
        b_ih + 0 * 2 * 24, b_hh + 0 * 2 * 24, ns);
    gru_scan<16, false, true, false><<<blk2, 256, 0, stream>>>(
        (const void*)bufB, bufA, nullptr, len_sorted + s0, order + s0,
        w_ih + 1 * 2 * 24 * 16, w_hh + 1 * 2 * 24 * 8,
        b_ih + 1 * 2 * 24, b_hh + 1 * 2 * 24, ns);
    gru_scan<16, false, false, true><<<blk1f, 256, 0, stream>>>(
        (const void*)bufA, nullptr, feat, len_sorted + s0, order + s0,
        w_ih + 2 * 2 * 24 * 16, w_hh + 2 * 2 * 24 * 8,
        b_ih + 2 * 2 * 24, b_hh + 2 * 2 * 24, ns);
    hipLaunchKernelGGL(bwd_last, dim3(blk1), dim3(256), 0, stream,
                       bufA, feat, len_sorted + s0, order + s0,
                       w_ih + 2 * 2 * 24 * 16, b_ih + 2 * 2 * 24, b_hh + 2 * 2 * 24, ns);
  }
  hipLaunchKernelGGL(head_kernel, dim3((NN + 255) / 256), dim3(256), 0, stream,
                     feat, lin1_w, lin1_b, lin2_w, lin2_b, out);
}

// Round 10
// 414.766 us; speedup vs baseline: 1.3670x; 1.1143x over previous
//
#include <hip/hip_runtime.h>

#define BB 32
#define DD 400
#define KK 200
#define NN (BB*KK)
#define NBINS 512
#define NSIMD 1024  // 256 CU x 4 SIMD

typedef float f2 __attribute__((ext_vector_type(2)));
typedef _Float16 half_t;
typedef _Float16 f16x2 __attribute__((ext_vector_type(2)));

#if defined(__has_builtin)
#if __has_builtin(__builtin_amdgcn_fdot2)
#define HAVE_FDOT2 1
#endif
#endif

__device__ __forceinline__ float dot2(f16x2 w, f16x2 v, float acc) {
#ifdef HAVE_FDOT2
  return __builtin_amdgcn_fdot2(w, v, acc, false);
#else
  return fmaf((float)w.x, (float)v.x, fmaf((float)w.y, (float)v.y, acc));
#endif
}

__device__ __forceinline__ float fast_sigmoid(float x) {
  float e = __builtin_amdgcn_exp2f(-1.4426950408889634f * x);
  return __builtin_amdgcn_rcpf(1.0f + e);
}
__device__ __forceinline__ float fast_tanh(float x) {
  float e = __builtin_amdgcn_exp2f(-2.8853900817779268f * x);
  return 2.0f * __builtin_amdgcn_rcpf(1.0f + e) - 1.0f;
}

// quad_perm broadcast P within each aligned 4-lane quad (VALU pipe)
#define QPERM(v, P) __int_as_float(__builtin_amdgcn_mov_dpp(__float_as_int(v), (P)*0x55, 0xF, 0xF, true))
// ROW_HALF_MIRROR: lane i reads lane i^7 within each 8-lane half-row (VALU pipe, no LDS)
#define HMIRROR(v) __int_as_float(__builtin_amdgcn_mov_dpp(__float_as_int(v), 0x141, 0xF, 0xF, true))

// x (B, D, K) -> xt[(b*K+k)*D + t] = x[b][t][k]
__global__ __launch_bounds__(256) void transpose_x(const float* __restrict__ x,
                                                   float* __restrict__ xt) {
  __shared__ float tile[32][33];
  int b = blockIdx.x, t0 = blockIdx.y * 32, k0 = blockIdx.z * 32;
  int tx = threadIdx.x, ty = threadIdx.y;
#pragma unroll
  for (int i = 0; i < 32; i += 8) {
    int t = t0 + ty + i, k = k0 + tx;
    tile[ty + i][tx] = (t < DD && k < KK) ? x[((size_t)b * DD + t) * KK + k] : 0.0f;
  }
  __syncthreads();
#pragma unroll
  for (int i = 0; i < 32; i += 8) {
    int k = k0 + ty + i, t = t0 + tx;
    if (k < KK && t < DD) xt[((size_t)b * KK + k) * DD + t] = tile[tx][ty + i];
  }
}

// first zero index (else D) per sequence + length histogram
__global__ __launch_bounds__(64) void compute_lengths(const float* __restrict__ xt,
                                                      int* __restrict__ lengths,
                                                      int* __restrict__ hist) {
  int n = blockIdx.x, lane = threadIdx.x;
  int m = DD;
  for (int t = lane; t < DD; t += 64) {
    if (xt[(size_t)n * DD + t] == 0.0f) { m = t; break; }
  }
#pragma unroll
  for (int off = 1; off < 64; off <<= 1) {
    int o = __shfl_xor(m, off, 64);
    m = (o < m) ? o : m;
  }
  if (lane == 0) {
    lengths[n] = m;
    atomicAdd(&hist[m], 1);
  }
}

// wave-parallel exclusive prefix scan over 512 bins (8 bins/lane + shfl scan)
__global__ __launch_bounds__(64) void scan_offsets(const int* __restrict__ hist,
                                                   int* __restrict__ offs) {
  int lane = threadIdx.x;
  int v[8], tot = 0;
#pragma unroll
  for (int i = 0; i < 8; ++i) { v[i] = tot; tot += hist[lane * 8 + i]; }
  int incl = tot;
#pragma unroll
  for (int off = 1; off < 64; off <<= 1) {
    int oth = __shfl_up(incl, off, 64);
    if (lane >= off) incl += oth;
  }
  int excl = incl - tot;
#pragma unroll
  for (int i = 0; i < 8; ++i) offs[lane * 8 + i] = excl + v[i];
}

__global__ __launch_bounds__(256) void scatter_sort(const int* __restrict__ lengths,
                                                    int* __restrict__ offs,
                                                    int* __restrict__ order,
                                                    int* __restrict__ len_sorted) {
  int n = blockIdx.x * 256 + threadIdx.x;
  if (n >= NN) return;
  int len = lengths[n];
  int pos = atomicAdd(&offs[len], 1);
  order[pos] = n;
  len_sorted[pos] = len;
}

// SIMD-aware wave->octet mapping. Blocks are 1 wave (64 thr); MI355X round-robins
// blocks over 8 XCDs, so 128 consecutive . . p and p+NSIMD share a SIMD.
// E = W-NSIMD extras pair with positions [0,E): give singles the longest octets,
// pair major (rank W-1025+E-p) with minor (rank p-1024) -> per-SIMD sum ~= const.
__device__ __forceinline__ int octet_of_wave(int p, int W) {
  int E = W - NSIMD;
  if (E <= 0) return W - 1 - p;                 // all singles: desc
  if (p >= NSIMD) return p - NSIMD;             // pair minor: shortest E
  if (p >= E) return W - 1 - (p - E);           // singles: longest
  return (W - 1 - NSIMD + E) - p;               // pair major
}

// 8 lanes per (sorted-seq, dir); lane li owns hidden unit li. 1 wave per block.
// h-exchange: ALL-DPP (half_mirror + quad_perm) -> zero LDS ops in the scan loop.
// QPERM(HMIRROR(h), P) = h[(qb+P)^7], so wAB.y uses Whh column (qb+P)^7.
// Inter-layer streams f16; gi dots via v_dot2_f32_f16. 4-step register prefetch.
template <int IN_DIM, bool IND_IN, bool WRITE_SEQ, bool FWD_ONLY>
__global__ __launch_bounds__(64) void gru_scan(
    const void* __restrict__ in, half_t* __restrict__ out, float* __restrict__ feat,
    const int* __restrict__ len_sorted, const int* __restrict__ order,
    const float* __restrict__ Wih, const float* __restrict__ Whh,
    const float* __restrict__ bih, const float* __restrict__ bhh, int nseq) {
  int p = blockIdx.x;                 // one wave per block
  int lane = threadIdx.x & 63;
  int G = FWD_ONLY ? nseq : nseq * 2;
  int W = (G + 7) >> 3;
  if (p >= W) return;
  int o = octet_of_wave(p, W);
  int gidx = o * 8 + (lane >> 3);
  int li = lane & 7;
  if (gidx >= G) return;
  int sg  = FWD_ONLY ? gidx : (gidx >> 1);
  int dir = FWD_ONLY ? 0 : (gidx & 1);
  int len = len_sorted[sg];

  int qb = li & 4;
  f2 wAB[3][4];       // {wA: col qb+P, wB: col (qb+P)^7} for packed gh
  f16x2 wi2[3][8];
  float wi1[3];
  float bs[3], bh2;   // bs[0..1] = bih+bhh, bs[2] = bih; bh2 = bhh n-gate
#pragma unroll
  for (int gt = 0; gt < 3; ++gt) {
    int row = dir * 24 + gt * 8 + li;
    if constexpr (IN_DIM == 16) {
#pragma unroll
      for (int q = 0; q < 8; ++q) {
        f16x2 w;
        w.x = (half_t)Wih[row * 16 + 2 * q];
        w.y = (half_t)Wih[row * 16 + 2 * q + 1];
        wi2[gt][q] = w;
      }
    } else {
      wi1[gt] = Wih[row];
    }
#pragma unroll
    for (int P = 0; P < 4; ++P) {
      f2 w;
      w.x = Whh[row * 8 + qb + P];
      w.y = Whh[row * 8 + ((qb + P) ^ 7)];
      wAB[gt][P] = w;
    }
    bs[gt] = bih[row] + ((gt < 2) ? bhh[row] : 0.0f);
    if (gt == 2) bh2 = bhh[row];
  }

  int steps = len;  // >= 200 always
  float h = 0.0f;

  const float* px = nullptr;
  const half_t* pxh = nullptr;
  ptrdiff_t xstep;
  if constexpr (IN_DIM == 1) {
    const float* basep = (const float*)in + (IND_IN ? (size_t)order[sg] * DD : (size_t)sg * DD);
    px = basep + ((dir == 0) ? 0 : (len - 1));
    xstep = (dir == 0) ? 1 : -1;
  } else {
    const half_t* basep = (const half_t*)in + (size_t)sg * DD * 16;
    pxh = basep + (size_t)((dir == 0) ? 0 : (len - 1)) * 16;
    xstep = (dir == 0) ? 16 : -16;
  }

  half_t* pw = nullptr; ptrdiff_t wstep = 0;
  if constexpr (WRITE_SEQ) {
    pw = out + ((size_t)sg * DD + ((dir == 0) ? 0 : (len - 1))) * 16 + dir * 8 + li;
    wstep = (dir == 0) ? 16 : -16;
  }

  // shared epilogue: all-DPP h-gather, tree-reduced packed gh, activations, h update
  auto core = [&](float a0, float a1, float a2) {
    float hm = HMIRROR(h);  // lane i^7's h (cross-quad), pure VALU
    float hq0 = QPERM(h, 0), hq1 = QPERM(h, 1), hq2 = QPERM(h, 2), hq3 = QPERM(h, 3);
    float hx0 = QPERM(hm, 0), hx1 = QPERM(hm, 1), hx2 = QPERM(hm, 2), hx3 = QPERM(hm, 3);
    f2 u0; u0.x = hq0; u0.y = hx0;
    f2 u1; u1.x = hq1; u1.y = hx1;
    f2 u2; u2.x = hq2; u2.y = hx2;
    f2 u3; u3.x = hq3; u3.y = hx3;

    // tree: (w0*u0 + w1*u1) + (w2*u2 + w3*u3) -> 2-deep FMA + 1 add
    f2 c0a = wAB[0][0] * u0; c0a += wAB[0][1] * u1;
    f2 c0b = wAB[0][2] * u2; c0b += wAB[0][3] * u3;
    f2 c0 = c0a + c0b;
    f2 c1a = wAB[1][0] * u0; c1a += wAB[1][1] * u1;
    f2 c1b = wAB[1][2] * u2; c1b += wAB[1][3] * u3;
    f2 c1 = c1a + c1b;
    f2 c2a = wAB[2][0] * u0; c2a += wAB[2][1] * u1;
    f2 c2b = wAB[2][2] * u2; c2b += wAB[2][3] * u3;
    f2 c2 = c2a + c2b;

    float r = fast_sigmoid(a0 + c0.x + c0.y);
    float z = fast_sigmoid(a1 + c1.x + c1.y);
    float n = fast_tanh(a2 + r * (bh2 + c2.x + c2.y));
    h = z * (h - n) + n;  // == (1-z)*n + z*h
    if constexpr (WRITE_SEQ) { *pw = (half_t)h; pw += wstep; }
  };

  if constexpr (IN_DIM == 1) {
    float s0_, s1_, s2_, s3_;
    auto ld = [&](float& S_) { S_ = *px; px += xstep; };
    auto st = [&](float& S_, bool pf) {
      float a0 = fmaf(wi1[0], S_, bs[0]);
      float a1 = fmaf(wi1[1], S_, bs[1]);
      float a2 = fmaf(wi1[2], S_, bs[2]);
      if (pf) ld(S_);
      core(a0, a1, a2);
    };
    ld(s0_); ld(s1_); ld(s2_); ld(s3_);
    int t = 0;
    for (; t + 4 <= steps; t += 4) {
      st(s0_, true); st(s1_, true); st(s2_, true); st(s3_, true);
    }
    int rem = steps - t;
    if (rem > 0) st(s0_, false);
    if (rem > 1) st(s1_, false);
    if (rem > 2) st(s2_, false);
  } else {
    uint4 b0_[2], b1_[2], b2_[2], b3_[2];
    auto ld = [&](uint4 (&B_)[2]) {
      const uint4* q4 = reinterpret_cast<const uint4*>(pxh);
      B_[0] = q4[0]; B_[1] = q4[1];
      pxh += xstep;
    };
    auto st = [&](uint4 (&B_)[2], bool pf) {
      float a0 = bs[0], a1 = bs[1], a2 = bs[2];
#pragma unroll
      for (int q = 0; q < 2; ++q) {
        f16x2 p0 = __builtin_bit_cast(f16x2, B_[q].x);
        f16x2 p1 = __builtin_bit_cast(f16x2, B_[q].y);
        f16x2 p2 = __builtin_bit_cast(f16x2, B_[q].z);
        f16x2 p3 = __builtin_bit_cast(f16x2, B_[q].w);
        a0 = dot2(wi2[0][4*q], p0, a0); a0 = dot2(wi2[0][4*q+1], p1, a0);
        a0 = dot2(wi2[0][4*q+2], p2, a0); a0 = dot2(wi2[0][4*q+3], p3, a0);
        a1 = dot2(wi2[1][4*q], p0, a1); a1 = dot2(wi2[1][4*q+1], p1, a1);
        a1 = dot2(wi2[1][4*q+2], p2, a1); a1 = dot2(wi2[1][4*q+3], p3, a1);
        a2 = dot2(wi2[2][4*q], p0, a2); a2 = dot2(wi2[2][4*q+1], p1, a2);
        a2 = dot2(wi2[2][4*q+2], p2, a2); a2 = dot2(wi2[2][4*q+3], p3, a2);
      }
      if (pf) ld(B_);
      core(a0, a1, a2);
    };
    ld(b0_); ld(b1_); ld(b2_); ld(b3_);
    int t = 0;
    for (; t + 4 <= steps; t += 4) {
      st(b0_, true); st(b1_, true); st(b2_, true); st(b3_, true);
    }
    int rem = steps - t;
    if (rem > 0) st(b0_, false);
    if (rem > 1) st(b1_, false);
    if (rem > 2) st(b2_, false);
  }

  if constexpr (!WRITE_SEQ) {
    feat[(size_t)order[sg] * 16 + dir * 8 + li] = h;
  }
}

// last layer, bwd direction: only t = len-1 matters and h0 = 0 => gh = bhh (closed form)
__global__ __launch_bounds__(256) void bwd_last(
    const half_t* __restrict__ in, float* __restrict__ feat,
    const int* __restrict__ len_sorted, const int* __restrict__ order,
    const float* __restrict__ Wih, const float* __restrict__ bih,
    const float* __restrict__ bhh, int nseq) {
  int tid = blockIdx.x * blockDim.x + threadIdx.x;
  int sg = tid >> 3, li = tid & 7;
  if (sg >= nseq) return;
  int len = len_sorted[sg];
  const half_t* xp = in + ((size_t)sg * DD + (len - 1)) * 16;
  float xv[16];
#pragma unroll
  for (int j = 0; j < 16; ++j) xv[j] = (float)xp[j];
  float a[3], bh[3];
#pragma unroll
  for (int gt = 0; gt < 3; ++gt) {
    int row = 24 + gt * 8 + li;  // dir=1 rows
    const float* wp = Wih + row * 16;
    float acc = bih[row];
#pragma unroll
    for (int j = 0; j < 16; ++j) acc = fmaf(wp[j], xv[j], acc);
    a[gt] = acc;
    bh[gt] = bhh[row];
  }
  float r = fast_sigmoid(a[0] + bh[0]);
  float z = fast_sigmoid(a[1] + bh[1]);
  float n = fast_tanh(a[2] + r * bh[2]);
  float h = (1.0f - z) * n;
  feat[(size_t)order[sg] * 16 + 8 + li] = h;
}

__global__ __launch_bounds__(256) void head_kernel(
    const float* __restrict__ feat, const float* __restrict__ w1,
    const float* __restrict__ b1, const float* __restrict__ w2,
    const float* __restrict__ b2, float* __restrict__ out) {
  int n = blockIdx.x * blockDim.x + threadIdx.x;
  if (n >= NN) return;
  float f[16];
  const float4* p = reinterpret_cast<const float4*>(feat + (size_t)n * 16);
#pragma unroll
  for (int q = 0; q < 4; ++q) {
    float4 v = p[q];
    f[4*q] = v.x; f[4*q+1] = v.y; f[4*q+2] = v.z; f[4*q+3] = v.w;
  }
  float y[8];
#pragma unroll
  for (int o = 0; o < 8; ++o) {
    float s = b1[o];
#pragma unroll
    for (int j = 0; j < 16; ++j) s += f[j] * w1[o * 16 + j];
    y[o] = (s > 0.0f) ? s : 0.2f * s;
  }
#pragma unroll
  for (int o2 = 0; o2 < 8; ++o2) {
    float s = b2[o2];
#pragma unroll
    for (int o = 0; o < 8; ++o) s += y[o] * w2[o2 * 8 + o];
    out[(size_t)n * 8 + o2] = s;
  }
}

extern "C" void kernel_launch(void* const* d_in, const int* in_sizes, int n_in,
                              void* d_out, int out_size, void* d_ws, size_t ws_size,
                              hipStream_t stream) {
  const float* x      = (const float*)d_in[0];
  const float* w_ih0  = (const float*)d_in[1];
  const float* w_hh0  = (const float*)d_in[2];
  const float* b_ih0  = (const float*)d_in[3];
  const float* b_hh0  = (const float*)d_in[4];
  const float* w_ih   = (const float*)d_in[5];
  const float* w_hh   = (const float*)d_in[6];
  const float* b_ih   = (const float*)d_in[7];
  const float* b_hh   = (const float*)d_in[8];
  const float* lin1_w = (const float*)d_in[9];
  const float* lin1_b = (const float*)d_in[10];
  const float* lin2_w = (const float*)d_in[11];
  const float* lin2_b = (const float*)d_in[12];
  float* out = (float*)d_out;

  char* ws = (char*)d_ws;
  size_t off = 0;
  auto alloc = [&](size_t bytes) -> void* {
    void* p = ws + off;
    off += (bytes + 255) & ~(size_t)255;
    return p;
  };
  alloc(1024);  // front guard (backward prefetch overrun)
  float* xt         = (float*)alloc((size_t)NN * DD * sizeof(float) + 1024);
  int*   lengths    = (int*)  alloc((size_t)NN * sizeof(int));
  int*   hist       = (int*)  alloc(NBINS * sizeof(int));
  int*   offs       = (int*)  alloc(NBINS * sizeof(int));
  int*   order      = (int*)  alloc((size_t)NN * sizeof(int));
  int*   len_sorted = (int*)  alloc((size_t)NN * sizeof(int));
  float* feat       = (float*)alloc((size_t)NN * 16 * sizeof(float));
  size_t base = off;
  size_t per_seq = (size_t)DD * 16 * sizeof(half_t) * 2 + 1024;  // two f16 ping-pong buffers
  int Nc = NN;
  if (base + (size_t)NN * per_seq + 8192 > ws_size) {
    size_t avail = (ws_size > base + 8192) ? (ws_size - base - 8192) : 0;
    size_t nc = avail / per_seq;
    if (nc < 1) nc = 1;
    if (nc > (size_t)NN) nc = NN;
    Nc = (int)nc;
  }
  alloc(1024);  // guard before bufA
  half_t* bufA = (half_t*)alloc((size_t)Nc * DD * 16 * sizeof(half_t) + 1024);
  half_t* bufB = (half_t*)alloc((size_t)Nc * DD * 16 * sizeof(half_t) + 1024);

  hipMemsetAsync(hist, 0, NBINS * sizeof(int), stream);
  dim3 gT(BB, (DD + 31) / 32, (KK + 31) / 32), bT(32, 8, 1);
  hipLaunchKernelGGL(transpose_x, gT, bT, 0, stream, x, xt);
  hipLaunchKernelGGL(compute_lengths, dim3(NN), dim3(64), 0, stream, xt, lengths, hist);
  hipLaunchKernelGGL(scan_offsets, dim3(1), dim3(64), 0, stream, hist, offs);
  hipLaunchKernelGGL(scatter_sort, dim3((NN + 255) / 256), dim3(256), 0, stream,
                     lengths, offs, order, len_sorted);

  for (int s0 = 0; s0 < NN; s0 += Nc) {
    int ns = (NN - s0 < Nc) ? (NN - s0) : Nc;
    int W2 = (ns * 2 + 7) / 8;           // bidir wave count (1 wave per block)
    int W1 = (ns + 7) / 8;               // fwd-only wave count
    int blk1 = (ns * 8 + 255) / 256;     // bwd_last
    gru_scan<1, true, true, false><<<W2, 64, 0, stream>>>(
        (const void*)xt, bufA, nullptr, len_sorted + s0, order + s0,
        w_ih0, w_hh0, b_ih0, b_hh0, ns);
    gru_scan<16, false, true, false><<<W2, 64, 0, stream>>>(
        (const void*)bufA, bufB, nullptr, len_sorted + s0, order + s0,
        w_ih + 0 * 2 * 24 * 16, w_hh + 0 * 2 * 24 * 8,
        b_ih + 0 * 2 * 24, b_hh + 0 * 2 * 24, ns);
    gru_scan<16, false, true, false><<<W2, 64, 0, stream>>>(
        (const void*)bufB, bufA, nullptr, len_sorted + s0, order + s0,
        w_ih + 1 * 2 * 24 * 16, w_hh + 1 * 2 * 24 * 8,
        b_ih + 1 * 2 * 24, b_hh + 1 * 2 * 24, ns);
    gru_scan<16, false, false, true><<<W1, 64, 0, stream>>>(
        (const void*)bufA, nullptr, feat, len_sorted + s0, order + s0,
        w_ih + 2 * 2 * 24 * 16, w_hh + 2 * 2 * 24 * 8,
        b_ih + 2 * 2 * 24, b_hh + 2 * 2 * 24, ns);
    hipLaunchKernelGGL(bwd_last, dim3(blk1), dim3(256), 0, stream,
                       bufA, feat, len_sorted + s0, order + s0,
                       w_ih + 2 * 2 * 24 * 16, b_ih + 2 * 2 * 24, b_hh + 2 * 2 * 24, ns);
  }
  hipLaunchKernelGGL(head_kernel, dim3((NN + 255) / 256), dim3(256), 0, stream,
                     feat, lin1_w, lin1_b, lin2_w, lin2_b, out);
}